// Round 2
// baseline (323.201 us; speedup 1.0000x reference)
//
#include <hip/hip_runtime.h>
#include <stdint.h>

typedef __attribute__((ext_vector_type(8))) short s16x8;
typedef __attribute__((ext_vector_type(4))) float f32x4;
typedef unsigned short u16;

#define DEV static __device__ __forceinline__

DEV f32x4 mfma16(s16x8 a, s16x8 b, f32x4 c) {
    return __builtin_amdgcn_mfma_f32_16x16x32_bf16(a, b, c, 0, 0, 0);
}

DEV void gld16(const void* g, void* l) {
    __builtin_amdgcn_global_load_lds(
        (const __attribute__((address_space(1))) void*)g,
        (__attribute__((address_space(3))) void*)l, 16, 0, 0);
}

DEV u16 f2bf(float x) {
    union { float f; unsigned u; } v; v.f = x;
    unsigned r = v.u + 0x7FFFu + ((v.u >> 16) & 1u);
    return (u16)(r >> 16);
}
DEV float bf2f(u16 h) { return __uint_as_float(((unsigned)h) << 16); }

#define SBAR() do { __builtin_amdgcn_sched_barrier(0); __builtin_amdgcn_s_barrier(); __builtin_amdgcn_sched_barrier(0); } while (0)
#define LGKM0() asm volatile("s_waitcnt lgkmcnt(0)" ::: "memory")

// ---------------- weight / input conversion ----------------
struct WPtrs { const float* p[16]; };

__global__ void k_conv_w(WPtrs wp, u16* wd, u16* wq) {
    int t = blockIdx.x * 256 + threadIdx.x;
    int mat = t >> 14;
    int e = (t & 16383) << 2;
    const float* s = wp.p[mat] + e;
    u16* d = (mat < 8 ? wd + mat * 65536 : wq + (mat - 8) * 65536) + e;
    float4 v = *(const float4*)s;
    d[0] = f2bf(v.x); d[1] = f2bf(v.y); d[2] = f2bf(v.z); d[3] = f2bf(v.w);
}

__global__ void k_conv_x(const float* dn, const float* qn, u16* xd, u16* xq) {
    int t = blockIdx.x * 256 + threadIdx.x;
    int h = t >> 19;
    int e = (t & 524287) << 2;
    const float* s = (h ? qn : dn) + e;
    u16* d = (h ? xq : xd) + e;
    float4 v = *(const float4*)s;
    d[0] = f2bf(v.x); d[1] = f2bf(v.y); d[2] = f2bf(v.z); d[3] = f2bf(v.w);
}

// ---------------- projection GEMM: out = X @ W^T ----------------
__global__ __launch_bounds__(256, 1) void k_proj(const u16* xd, const u16* xq,
        const u16* wdm, const u16* wqm, u16* tokd, u16* tokq, u16* vtd, u16* vtq) {
    __shared__ __align__(16) char smem[16384];
    char* As = smem; char* Bs = smem + 8192;
    const int lane = threadIdx.x & 63, wid = threadIdx.x >> 6;
    const int z = blockIdx.z, grp = z >> 3, w = z & 7;
    const u16* X = grp ? xq : xd;
    const u16* W = (grp ? wqm : wdm) + w * 65536;
    const int m0 = blockIdx.x * 128, n0 = blockIdx.y * 128;
    const int wr = wid >> 1, wc = wid & 1;
    const int rl = lane & 15, g = lane >> 4;
    const f32x4 fz = {0.f, 0.f, 0.f, 0.f};
    f32x4 acc[4][4];
#pragma unroll
    for (int i = 0; i < 4; ++i)
#pragma unroll
        for (int j = 0; j < 4; ++j) acc[i][j] = fz;

    for (int kt = 0; kt < 8; ++kt) {
#pragma unroll
        for (int t = 0; t < 2; ++t) {
            int iid = wid * 2 + t;
            int ldso = iid * 1024 + lane * 16;
            int row = ldso >> 6, inrow = ldso & 63;
            int src = inrow ^ ((row & 3) << 4);
            gld16((const char*)X + ((size_t)(m0 + row) * 512 + kt * 64 + src), As + iid * 1024);
            gld16((const char*)W + ((size_t)(n0 + row) * 512 + kt * 64 + src), Bs + iid * 1024);
        }
        __syncthreads();
        s16x8 av[4], bv[4];
#pragma unroll
        for (int rf = 0; rf < 4; ++rf) {
            int row = wr * 64 + rf * 16 + rl;
            av[rf] = *(const s16x8*)(As + row * 64 + ((g * 16) ^ ((row & 3) << 4)));
        }
#pragma unroll
        for (int cf = 0; cf < 4; ++cf) {
            int row = wc * 64 + cf * 16 + rl;
            bv[cf] = *(const s16x8*)(Bs + row * 64 + ((g * 16) ^ ((row & 3) << 4)));
        }
#pragma unroll
        for (int rf = 0; rf < 4; ++rf)
#pragma unroll
            for (int cf = 0; cf < 4; ++cf)
                acc[rf][cf] = mfma16(av[rf], bv[cf], acc[rf][cf]);
        __syncthreads();
    }
    if (w < 4) {
        u16* out = (grp ? tokq : tokd) + (size_t)w * 2097152;
#pragma unroll
        for (int rf = 0; rf < 4; ++rf)
#pragma unroll
            for (int cf = 0; cf < 4; ++cf) {
                int n = n0 + wc * 64 + cf * 16 + rl;
                int m = m0 + wr * 64 + rf * 16 + g * 4;
#pragma unroll
                for (int r = 0; r < 4; ++r)
                    out[(size_t)(m + r) * 256 + n] = f2bf(acc[rf][cf][r]);
            }
    } else {
        u16* out = (grp ? vtq : vtd) + (size_t)(w - 4) * 2097152;
#pragma unroll
        for (int rf = 0; rf < 4; ++rf)
#pragma unroll
            for (int cf = 0; cf < 4; ++cf) {
                int n = n0 + wc * 64 + cf * 16 + rl;
                int m = m0 + wr * 64 + rf * 16 + g * 4;
                int b = m >> 10, tok = m & 1023;
                unsigned lo = (unsigned)f2bf(acc[rf][cf][0]) | ((unsigned)f2bf(acc[rf][cf][1]) << 16);
                unsigned hi = (unsigned)f2bf(acc[rf][cf][2]) | ((unsigned)f2bf(acc[rf][cf][3]) << 16);
                uint2 u; u.x = lo; u.y = hi;
                *(uint2*)(out + ((size_t)(b * 256 + n)) * 1024 + tok) = u;
            }
    }
}

// ---------------- fused masked attention + aggregation ----------------
struct PhaseCfg {
    const void* Q; const u16* K; const u16* Vl; const u16* Vr;
    const int* rm; const int* cm;
    int roff, coff; float scale;
    float* io; float* nbOut; const float* nbIn; const u16* selfTok;
};

// Dynamic LDS layout (109312 B):
//   Kb[2]  @ 0      (2 x 16384)   [32 j][512B] swz ^((j&7)<<4)
//   Vlb[2] @ 32768  (2 x 16384)   [256 ch][64B] swz ^((c&3)<<4)
//   Vrb[2] @ 65536  (2 x 16384)
//   Pls @ 98304, Prs @ 103424 (64 rows x 80B)
//   rsS @ 108544, dnS @ 108800, nbS @ 109056
template<bool FINAL>
__global__ __launch_bounds__(256, 1) void k_attn(PhaseCfg c0, PhaseCfg c1,
        const int* ner, const int* graph, const float* bias) {
    const PhaseCfg c = blockIdx.z ? c1 : c0;
    const int b = blockIdx.y;
    const int i0 = blockIdx.x * 64;
    const int lane = threadIdx.x & 63, wid = threadIdx.x >> 6;
    const int rl = lane & 15, g = lane >> 4;

    extern __shared__ char smem[];
    u16* Pls = (u16*)(smem + 98304);
    u16* Prs = (u16*)(smem + 103424);
    float* rsS = (float*)(smem + 108544);
    float* dnS = (float*)(smem + 108800);
    float* nbS = (float*)(smem + 109056);

    // Q fragments: rows = i0 + wid*16 + rl, k = kf*32 + g*8 .. +8
    s16x8 qf[8];
    {
        int qrow = i0 + wid * 16 + rl;
        if (FINAL) {
            const float* Qp = (const float*)c.Q + (size_t)(b * 1024 + qrow) * 256 + g * 8;
#pragma unroll
            for (int kf = 0; kf < 8; ++kf) {
                float4 x = *(const float4*)(Qp + kf * 32);
                float4 y = *(const float4*)(Qp + kf * 32 + 4);
                s16x8 t;
                t[0]=(short)f2bf(x.x); t[1]=(short)f2bf(x.y); t[2]=(short)f2bf(x.z); t[3]=(short)f2bf(x.w);
                t[4]=(short)f2bf(y.x); t[5]=(short)f2bf(y.y); t[6]=(short)f2bf(y.z); t[7]=(short)f2bf(y.w);
                qf[kf] = t;
            }
        } else {
            const u16* Qb = (const u16*)c.Q + (size_t)(b * 1024 + qrow) * 256 + g * 8;
#pragma unroll
            for (int kf = 0; kf < 8; ++kf) qf[kf] = *(const s16x8*)(Qb + kf * 32);
        }
    }
    const int iqb = i0 + wid * 16 + g * 4;
    int rmv[4];
#pragma unroll
    for (int r = 0; r < 4; ++r)
        rmv[r] = c.rm[b * 1024 + iqb + r] != 0;

    const size_t mb0 = ((size_t)(b * 2048 + c.roff + iqb)) * 2048 + c.coff;
    const int* nrb = ner + mb0;
    const int* grb = graph + mb0;
    const int* cmp = c.cm + b * 1024;

    const f32x4 fz = {0.f,0.f,0.f,0.f};
    f32x4 accl[4][4], accr[4][4];
#pragma unroll
    for (int i = 0; i < 4; ++i)
#pragma unroll
        for (int j = 0; j < 4; ++j) { accl[i][j] = fz; accr[i][j] = fz; }
    float mrow[4] = {-1e30f,-1e30f,-1e30f,-1e30f};
    float dden[4] = {0.f,0.f,0.f,0.f};
    float nbc[4]  = {0.f,0.f,0.f,0.f};

    const char* Kg  = (const char*)c.K  + (size_t)b * 524288;
    const char* Vlg = (const char*)c.Vl + (size_t)b * 524288;
    const char* Vrg = (const char*)c.Vr + (size_t)b * 524288;

    // stage j-tile into LDS buffer sel: 12 gld16 per wave (4 K + 4 Vl + 4 Vr)
    auto STAGE = [&](int j0, int sel) {
        char* Kd  = smem + sel * 16384;
        char* Vld = smem + 32768 + sel * 16384;
        char* Vrd = smem + 65536 + sel * 16384;
#pragma unroll
        for (int t = 0; t < 4; ++t) {
            int iid = wid * 4 + t;
            int ldso = iid * 1024 + lane * 16;
            int row = ldso >> 9, inrow = ldso & 511;
            int src = inrow ^ ((row & 7) << 4);
            gld16(Kg + ((size_t)(j0 + row) * 512 + src), Kd + iid * 1024);
        }
#pragma unroll
        for (int t = 0; t < 4; ++t) {
            int iid = wid * 4 + t;
            int ldso = iid * 1024 + lane * 16;
            int cc = ldso >> 6, in = ldso & 63;
            int src = in ^ ((cc & 3) << 4);
            gld16(Vlg + ((size_t)cc * 2048 + (size_t)j0 * 2 + src), Vld + iid * 1024);
            gld16(Vrg + ((size_t)cc * 2048 + (size_t)j0 * 2 + src), Vrd + iid * 1024);
        }
    };

    // mask regs for the CURRENT tile (loaded one iteration ahead, 18 loads)
    int mn0[4], mn1[4], mg0[4], mg1[4], mc0, mc1;
    auto MLOAD = [&](int j0) {
        int jq0 = j0 + rl, jq1 = j0 + 16 + rl;
#pragma unroll
        for (int r = 0; r < 4; ++r) {
            mn0[r] = nrb[r * 2048 + jq0];
            mn1[r] = nrb[r * 2048 + jq1];
            mg0[r] = grb[r * 2048 + jq0];
            mg1[r] = grb[r * 2048 + jq1];
        }
        mc0 = cmp[jq0]; mc1 = cmp[jq1];
    };

    STAGE(0, 0);
    MLOAD(0);

#pragma unroll 1
    for (int jt = 0; jt < 32; ++jt) {
        const int sel = jt & 1;
        const int j0 = jt * 32;
        if (jt < 31) {
            STAGE(j0 + 32, sel ^ 1);
            // in-flight: MLOAD(jt)[18] + STAGE(jt+1)[12]; STAGE(jt) retired at <=30
            asm volatile("s_waitcnt vmcnt(30)" ::: "memory");
        } else {
            // in-flight: tail of MLOAD(31)[18]; STAGE(31) retired at <=18
            asm volatile("s_waitcnt vmcnt(18)" ::: "memory");
        }
        SBAR();   // all waves: tile jt K/V in LDS

        const char* Ks  = smem + sel * 16384;
        const char* Vls = smem + 32768 + sel * 16384;
        const char* Vrs = smem + 65536 + sel * 16384;

        // S = Q K^T for wave's 16-row strip x 32 cols
        f32x4 s0 = fz, s1 = fz;
#pragma unroll
        for (int kk = 0; kk < 8; ++kk) {
            int jr0 = rl, jr1 = 16 + rl;
            s16x8 b0 = *(const s16x8*)(Ks + jr0 * 512 + ((kk * 64 + g * 16) ^ ((jr0 & 7) << 4)));
            s16x8 b1 = *(const s16x8*)(Ks + jr1 * 512 + ((kk * 64 + g * 16) ^ ((jr1 & 7) << 4)));
            s0 = mfma16(qf[kk], b0, s0);
            s1 = mfma16(qf[kk], b1, s1);
        }

        // masks + online softmax. frag element (row = 4g+r, col = rl)
        const int jq0 = j0 + rl, jq1 = j0 + 16 + rl;
        const int cm0 = mc0 != 0, cm1 = mc1 != 0;
        float sv0[4], sv1[4];
        int l0[4], l1[4], r0m[4], r1m[4];
#pragma unroll
        for (int r = 0; r < 4; ++r) {
            int iq = iqb + r;
            int n0v = mn0[r] != 0, n1v = mn1[r] != 0;
            int g0v = mg0[r] != 0, g1v = mg1[r] != 0;
            int v0 = rmv[r] & cm0 & n0v;
            int v1 = rmv[r] & cm1 & n1v;
            int e0 = FINAL ? v0 : (v0 & (int)(iq != jq0));
            int e1 = FINAL ? v1 : (v1 & (int)(iq != jq1));
            sv0[r] = v0 ? s0[r] * c.scale : -1e30f;
            sv1[r] = v1 ? s1[r] * c.scale : -1e30f;
            l0[r] = e0 & g0v;  r0m[r] = e0 & (g0v ^ 1);
            l1[r] = e1 & g1v;  r1m[r] = e1 & (g1v ^ 1);
            nbc[r] += (float)(e0 + e1);
        }
        float rsv[4];
#pragma unroll
        for (int r = 0; r < 4; ++r) {
            float t = fmaxf(sv0[r], sv1[r]);
            t = fmaxf(t, __shfl_xor(t, 1));
            t = fmaxf(t, __shfl_xor(t, 2));
            t = fmaxf(t, __shfl_xor(t, 4));
            t = fmaxf(t, __shfl_xor(t, 8));
            float mn = fmaxf(mrow[r], t);
            rsv[r] = __expf(mrow[r] - mn);
            mrow[r] = mn;
            float e0 = __expf(sv0[r] - mn);
            float e1 = __expf(sv1[r] - mn);
            dden[r] = dden[r] * rsv[r] + e0 + e1;
            int prow = wid * 16 + g * 4 + r;
            Pls[prow * 40 + rl]      = l0[r]  ? f2bf(e0) : (u16)0;
            Pls[prow * 40 + 16 + rl] = l1[r]  ? f2bf(e1) : (u16)0;
            Prs[prow * 40 + rl]      = r0m[r] ? f2bf(e0) : (u16)0;
            Prs[prow * 40 + 16 + rl] = r1m[r] ? f2bf(e1) : (u16)0;
        }
        if (rl == 0) {
            f32x4 rv = {rsv[0], rsv[1], rsv[2], rsv[3]};
            *(f32x4*)(rsS + wid * 16 + g * 4) = rv;
        }
        LGKM0();
        SBAR();   // P, rs visible

        // prefetch next tile's masks (consumed next iteration; hides HBM latency)
        if (jt < 31) MLOAD(j0 + 32);

        // PV: wave's 64-channel slice, rescale acc then accumulate
        f32x4 rs4[4];
#pragma unroll
        for (int rf = 0; rf < 4; ++rf) rs4[rf] = *(const f32x4*)(rsS + rf * 16 + g * 4);
#pragma unroll
        for (int rf = 0; rf < 4; ++rf)
#pragma unroll
            for (int cf = 0; cf < 4; ++cf) { accl[rf][cf] *= rs4[rf]; accr[rf][cf] *= rs4[rf]; }
        s16x8 pa[4], pb[4], va[4], vb[4];
#pragma unroll
        for (int rf = 0; rf < 4; ++rf) {
            pa[rf] = *(const s16x8*)((char*)Pls + (rf * 16 + rl) * 80 + g * 16);
            pb[rf] = *(const s16x8*)((char*)Prs + (rf * 16 + rl) * 80 + g * 16);
        }
#pragma unroll
        for (int cf = 0; cf < 4; ++cf) {
            int cc = wid * 64 + cf * 16 + rl;
            int off = (g * 16) ^ ((cc & 3) << 4);
            va[cf] = *(const s16x8*)(Vls + cc * 64 + off);
            vb[cf] = *(const s16x8*)(Vrs + cc * 64 + off);
        }
#pragma unroll
        for (int rf = 0; rf < 4; ++rf)
#pragma unroll
            for (int cf = 0; cf < 4; ++cf) {
                accl[rf][cf] = mfma16(pa[rf], va[cf], accl[rf][cf]);
                accr[rf][cf] = mfma16(pb[rf], vb[cf], accr[rf][cf]);
            }
        LGKM0();
        SBAR();   // WAR: all LDS reads done before next STAGE overwrites buf[sel^1]
    }

    // reduce row stats across the 16 lanes of each group
#pragma unroll
    for (int r = 0; r < 4; ++r) {
        float d = dden[r];
        d += __shfl_xor(d, 1); d += __shfl_xor(d, 2); d += __shfl_xor(d, 4); d += __shfl_xor(d, 8);
        dden[r] = d;
        float nn = nbc[r];
        nn += __shfl_xor(nn, 1); nn += __shfl_xor(nn, 2); nn += __shfl_xor(nn, 4); nn += __shfl_xor(nn, 8);
        nbc[r] = nn;
    }
    if (rl == 0) {
        f32x4 dv = {dden[0], dden[1], dden[2], dden[3]};
        *(f32x4*)(dnS + wid * 16 + g * 4) = dv;
        int idx = b * 1024 + i0 + wid * 16 + g * 4;
        if (!FINAL) {
            f32x4 nv = {nbc[0], nbc[1], nbc[2], nbc[3]};
            *(f32x4*)(c.nbOut + idx) = nv;
        } else {
            f32x4 nv = {nbc[0] + c.nbIn[idx], nbc[1] + c.nbIn[idx + 1],
                        nbc[2] + c.nbIn[idx + 2], nbc[3] + c.nbIn[idx + 3]};
            *(f32x4*)(nbS + wid * 16 + g * 4) = nv;
        }
    }
    __syncthreads();

    float bcol[4];
    if (FINAL) {
#pragma unroll
        for (int cf = 0; cf < 4; ++cf) bcol[cf] = bias[wid * 64 + cf * 16 + rl];
    }
#pragma unroll
    for (int rf = 0; rf < 4; ++rf) {
        f32x4 dv = *(const f32x4*)(dnS + rf * 16 + g * 4);
        f32x4 nbv = fz;
        if (FINAL) nbv = *(const f32x4*)(nbS + rf * 16 + g * 4);
#pragma unroll
        for (int cf = 0; cf < 4; ++cf) {
            int col = wid * 64 + cf * 16 + rl;
#pragma unroll
            for (int r = 0; r < 4; ++r) {
                int row = i0 + rf * 16 + g * 4 + r;
                size_t oi = (size_t)(b * 1024 + row) * 256 + col;
                float inv = dv[r] > 0.f ? 1.f / dv[r] : 0.f;
                float v = (accl[rf][cf][r] + accr[rf][cf][r]) * inv;
                if (!FINAL) {
                    c.io[oi] = v;
                } else {
                    float nb = fmaxf(nbv[r], 1.f);
                    float agg = (c.io[oi] + v) / nb;
                    float sf = bf2f(c.selfTok[oi]) + bcol[cf];
                    c.io[oi] = fmaxf(sf + agg, 0.f);
                }
            }
        }
    }
}

// ---------------- host ----------------
extern "C" void kernel_launch(void* const* d_in, const int* in_sizes, int n_in,
                              void* d_out, int out_size, void* d_ws, size_t ws_size,
                              hipStream_t stream) {
    (void)in_sizes; (void)n_in; (void)out_size; (void)ws_size;
    const float* d_node = (const float*)d_in[0];
    const float* q_node = (const float*)d_in[1];
    const float* b_self = (const float*)d_in[9];
    const int* dm = (const int*)d_in[18];
    const int* qm = (const int*)d_in[19];
    const int* ner = (const int*)d_in[20];
    const int* graph = (const int*)d_in[21];

    char* ws = (char*)d_ws;
    const size_t MB = 1024 * 1024;
    u16* xd   = (u16*)(ws + 0 * MB);
    u16* xq   = (u16*)(ws + 4 * MB);
    u16* wdm  = (u16*)(ws + 8 * MB);
    u16* wqm  = (u16*)(ws + 9 * MB);
    u16* tokd = (u16*)(ws + 10 * MB);
    u16* tokq = (u16*)(ws + 26 * MB);
    u16* vtd  = (u16*)(ws + 42 * MB);
    u16* vtq  = (u16*)(ws + 58 * MB);
    float* nbdd = (float*)(ws + 74 * MB);
    float* nbqq = (float*)(ws + 74 * MB + 32768);

    float* outd = (float*)d_out;
    float* outq = outd + 2097152;

    WPtrs wp;
    wp.p[0]  = (const float*)d_in[2];
    wp.p[1]  = (const float*)d_in[3];
    wp.p[2]  = (const float*)d_in[7];
    wp.p[3]  = (const float*)d_in[8];
    wp.p[4]  = (const float*)d_in[10];
    wp.p[5]  = (const float*)d_in[14];
    wp.p[6]  = (const float*)d_in[13];
    wp.p[7]  = (const float*)d_in[17];
    wp.p[8]  = (const float*)d_in[4];
    wp.p[9]  = (const float*)d_in[5];
    wp.p[10] = (const float*)d_in[6];
    wp.p[11] = (const float*)d_in[8];
    wp.p[12] = (const float*)d_in[11];
    wp.p[13] = (const float*)d_in[15];
    wp.p[14] = (const float*)d_in[12];
    wp.p[15] = (const float*)d_in[16];

    const int SMEM = 109312;
    (void)hipFuncSetAttribute((const void*)k_attn<false>,
        hipFuncAttributeMaxDynamicSharedMemorySize, SMEM);
    (void)hipFuncSetAttribute((const void*)k_attn<true>,
        hipFuncAttributeMaxDynamicSharedMemorySize, SMEM);

    k_conv_w<<<1024, 256, 0, stream>>>(wp, wdm, wqm);
    k_conv_x<<<4096, 256, 0, stream>>>(d_node, q_node, xd, xq);
    k_proj<<<dim3(64, 2, 16), 256, 0, stream>>>(xd, xq, wdm, wqm, tokd, tokq, vtd, vtq);

    const size_t M2 = 2097152;
    PhaseCfg dd = { tokd, tokd + M2, vtd, vtd + M2, dm, dm, 0, 0, 0.0625f,
                    outd, nbdd, nullptr, nullptr };
    PhaseCfg qq = { tokq, tokq + M2, vtq, vtq + M2, qm, qm, 1024, 1024, 0.0625f,
                    outq, nbqq, nullptr, nullptr };
    k_attn<false><<<dim3(16, 8, 2), 256, SMEM, stream>>>(dd, qq, ner, graph, b_self);

    PhaseCfg dq = { d_node, tokq + 2 * M2, vtq + 2 * M2, vtq + 3 * M2, dm, qm, 0, 1024, 1.0f,
                    outd, nullptr, nbdd, tokd + 3 * M2 };
    PhaseCfg qd = { q_node, tokd + 2 * M2, vtd + 2 * M2, vtd + 3 * M2, qm, dm, 1024, 0, 1.0f,
                    outq, nullptr, nbqq, tokq + 3 * M2 };
    k_attn<true><<<dim3(16, 8, 2), 256, SMEM, stream>>>(dq, qd, ner, graph, b_self);
}

// Round 3
// 257.460 us; speedup vs baseline: 1.2553x; 1.2553x over previous
//
#include <hip/hip_runtime.h>
#include <stdint.h>

typedef __attribute__((ext_vector_type(8))) short s16x8;
typedef __attribute__((ext_vector_type(4))) float f32x4;
typedef unsigned short u16;

#define DEV static __device__ __forceinline__

DEV f32x4 mfma16(s16x8 a, s16x8 b, f32x4 c) {
    return __builtin_amdgcn_mfma_f32_16x16x32_bf16(a, b, c, 0, 0, 0);
}

DEV void gld16(const void* g, void* l) {
    __builtin_amdgcn_global_load_lds(
        (const __attribute__((address_space(1))) void*)g,
        (__attribute__((address_space(3))) void*)l, 16, 0, 0);
}

DEV u16 f2bf(float x) {
    union { float f; unsigned u; } v; v.f = x;
    unsigned r = v.u + 0x7FFFu + ((v.u >> 16) & 1u);
    return (u16)(r >> 16);
}
DEV float bf2f(u16 h) { return __uint_as_float(((unsigned)h) << 16); }

#define SBAR() do { __builtin_amdgcn_sched_barrier(0); __builtin_amdgcn_s_barrier(); __builtin_amdgcn_sched_barrier(0); } while (0)
#define LGKM0() do { asm volatile("s_waitcnt lgkmcnt(0)" ::: "memory"); __builtin_amdgcn_sched_barrier(0); } while (0)

// ---------------- weight / input conversion ----------------
struct WPtrs { const float* p[16]; };

__global__ void k_conv_w(WPtrs wp, u16* wd, u16* wq) {
    int t = blockIdx.x * 256 + threadIdx.x;
    int mat = t >> 14;
    int e = (t & 16383) << 2;
    const float* s = wp.p[mat] + e;
    u16* d = (mat < 8 ? wd + mat * 65536 : wq + (mat - 8) * 65536) + e;
    float4 v = *(const float4*)s;
    d[0] = f2bf(v.x); d[1] = f2bf(v.y); d[2] = f2bf(v.z); d[3] = f2bf(v.w);
}

__global__ void k_conv_x(const float* dn, const float* qn, u16* xd, u16* xq) {
    int t = blockIdx.x * 256 + threadIdx.x;
    int h = t >> 19;
    int e = (t & 524287) << 2;
    const float* s = (h ? qn : dn) + e;
    u16* d = (h ? xq : xd) + e;
    float4 v = *(const float4*)s;
    d[0] = f2bf(v.x); d[1] = f2bf(v.y); d[2] = f2bf(v.z); d[3] = f2bf(v.w);
}

// ---------------- projection GEMM: out = X @ W^T ----------------
__global__ __launch_bounds__(256, 1) void k_proj(const u16* xd, const u16* xq,
        const u16* wdm, const u16* wqm, u16* tokd, u16* tokq, u16* vtd, u16* vtq) {
    __shared__ __align__(16) char smem[16384];
    char* As = smem; char* Bs = smem + 8192;
    const int lane = threadIdx.x & 63, wid = threadIdx.x >> 6;
    const int z = blockIdx.z, grp = z >> 3, w = z & 7;
    const u16* X = grp ? xq : xd;
    const u16* W = (grp ? wqm : wdm) + w * 65536;
    const int m0 = blockIdx.x * 128, n0 = blockIdx.y * 128;
    const int wr = wid >> 1, wc = wid & 1;
    const int rl = lane & 15, g = lane >> 4;
    const f32x4 fz = {0.f, 0.f, 0.f, 0.f};
    f32x4 acc[4][4];
#pragma unroll
    for (int i = 0; i < 4; ++i)
#pragma unroll
        for (int j = 0; j < 4; ++j) acc[i][j] = fz;

    for (int kt = 0; kt < 8; ++kt) {
#pragma unroll
        for (int t = 0; t < 2; ++t) {
            int iid = wid * 2 + t;
            int ldso = iid * 1024 + lane * 16;
            int row = ldso >> 6, inrow = ldso & 63;
            int src = inrow ^ ((row & 3) << 4);
            gld16((const char*)X + ((size_t)(m0 + row) * 512 + kt * 64 + src), As + iid * 1024);
            gld16((const char*)W + ((size_t)(n0 + row) * 512 + kt * 64 + src), Bs + iid * 1024);
        }
        __syncthreads();
        s16x8 av[4], bv[4];
#pragma unroll
        for (int rf = 0; rf < 4; ++rf) {
            int row = wr * 64 + rf * 16 + rl;
            av[rf] = *(const s16x8*)(As + row * 64 + ((g * 16) ^ ((row & 3) << 4)));
        }
#pragma unroll
        for (int cf = 0; cf < 4; ++cf) {
            int row = wc * 64 + cf * 16 + rl;
            bv[cf] = *(const s16x8*)(Bs + row * 64 + ((g * 16) ^ ((row & 3) << 4)));
        }
#pragma unroll
        for (int rf = 0; rf < 4; ++rf)
#pragma unroll
            for (int cf = 0; cf < 4; ++cf)
                acc[rf][cf] = mfma16(av[rf], bv[cf], acc[rf][cf]);
        __syncthreads();
    }
    if (w < 4) {
        u16* out = (grp ? tokq : tokd) + (size_t)w * 2097152;
#pragma unroll
        for (int rf = 0; rf < 4; ++rf)
#pragma unroll
            for (int cf = 0; cf < 4; ++cf) {
                int n = n0 + wc * 64 + cf * 16 + rl;
                int m = m0 + wr * 64 + rf * 16 + g * 4;
#pragma unroll
                for (int r = 0; r < 4; ++r)
                    out[(size_t)(m + r) * 256 + n] = f2bf(acc[rf][cf][r]);
            }
    } else {
        u16* out = (grp ? vtq : vtd) + (size_t)(w - 4) * 2097152;
#pragma unroll
        for (int rf = 0; rf < 4; ++rf)
#pragma unroll
            for (int cf = 0; cf < 4; ++cf) {
                int n = n0 + wc * 64 + cf * 16 + rl;
                int m = m0 + wr * 64 + rf * 16 + g * 4;
                int b = m >> 10, tok = m & 1023;
                unsigned lo = (unsigned)f2bf(acc[rf][cf][0]) | ((unsigned)f2bf(acc[rf][cf][1]) << 16);
                unsigned hi = (unsigned)f2bf(acc[rf][cf][2]) | ((unsigned)f2bf(acc[rf][cf][3]) << 16);
                uint2 u; u.x = lo; u.y = hi;
                *(uint2*)(out + ((size_t)(b * 256 + n)) * 1024 + tok) = u;
            }
    }
}

// ---------------- fused masked attention + aggregation ----------------
struct PhaseCfg {
    const void* Q; const u16* K; const u16* Vl; const u16* Vr;
    const int* rm; const int* cm;
    int roff, coff; float scale;
    float* io; float* nbOut; const float* nbIn; const u16* selfTok;
};

// BM=32, j-tile=32. 4 waves in 2x2: (ws = row strip 16, wc = col half 16).
// K double-buffered in LDS; V read direct from global (channel-major, L2);
// P double-buffered in LDS. 3 barriers/iter (A: K ready, M: max exchange,
// B: P ready).
// LDS: Ks[2] @0 (2x16384); Pl0@32768 Pl1@35328 Pr0@37888 Pr1@40448 (2560 ea);
//      mxS@43008(64f) rsS@43264(32f) dpS@43392(64f) nbpS@43648(64f)
template<bool FINAL>
__global__ __launch_bounds__(256, 2) void k_attn(PhaseCfg c0, PhaseCfg c1,
        const int* ner, const int* graph, const float* bias) {
    const PhaseCfg c = blockIdx.z ? c1 : c0;
    const int b = blockIdx.y;
    const int i0 = blockIdx.x * 32;
    const int lane = threadIdx.x & 63, w = threadIdx.x >> 6;
    const int ws = w >> 1, wc = w & 1;
    const int rl = lane & 15, g = lane >> 4;

    __shared__ __align__(16) char smem[43904];
    float* mxS  = (float*)(smem + 43008);
    float* rsS  = (float*)(smem + 43264);
    float* dpS  = (float*)(smem + 43392);
    float* nbpS = (float*)(smem + 43648);

    // Q fragments for the wave's 16-row strip: rows i0+ws*16+rl
    s16x8 qf[8];
    {
        int qrow = i0 + ws * 16 + rl;
        if (FINAL) {
            const float* Qp = (const float*)c.Q + (size_t)(b * 1024 + qrow) * 256 + g * 8;
#pragma unroll
            for (int kf = 0; kf < 8; ++kf) {
                float4 x = *(const float4*)(Qp + kf * 32);
                float4 y = *(const float4*)(Qp + kf * 32 + 4);
                s16x8 t;
                t[0]=(short)f2bf(x.x); t[1]=(short)f2bf(x.y); t[2]=(short)f2bf(x.z); t[3]=(short)f2bf(x.w);
                t[4]=(short)f2bf(y.x); t[5]=(short)f2bf(y.y); t[6]=(short)f2bf(y.z); t[7]=(short)f2bf(y.w);
                qf[kf] = t;
            }
        } else {
            const u16* Qb = (const u16*)c.Q + (size_t)(b * 1024 + qrow) * 256 + g * 8;
#pragma unroll
            for (int kf = 0; kf < 8; ++kf) qf[kf] = *(const s16x8*)(Qb + kf * 32);
        }
    }
    const int iqb = i0 + ws * 16 + g * 4;   // S-frag row base for this lane
    int rmv[4];
#pragma unroll
    for (int r = 0; r < 4; ++r)
        rmv[r] = c.rm[b * 1024 + iqb + r] != 0;

    // mask bases; column = coff + j0 + wc*16 + rl
    const size_t mb0 = ((size_t)(b * 2048 + c.roff + iqb)) * 2048 + c.coff + wc * 16;
    const int* nrb = ner + mb0;
    const int* grb = graph + mb0;
    const int* cmp = c.cm + b * 1024 + wc * 16;

    const f32x4 fz = {0.f,0.f,0.f,0.f};
    f32x4 accl[2][4], accr[2][4];
#pragma unroll
    for (int i = 0; i < 2; ++i)
#pragma unroll
        for (int j = 0; j < 4; ++j) { accl[i][j] = fz; accr[i][j] = fz; }
    float mrow[4] = {-1e30f,-1e30f,-1e30f,-1e30f};
    float dden[4] = {0.f,0.f,0.f,0.f};
    float nbc[4]  = {0.f,0.f,0.f,0.f};

    const char* Kg  = (const char*)c.K  + (size_t)b * 524288;
    const char* Vlg = (const char*)c.Vl + (size_t)b * 524288;
    const char* Vrg = (const char*)c.Vr + (size_t)b * 524288;

    // stage K j-tile (16KB): 4 gld16 per wave, linear dest, pre-swizzled src
    auto STAGE_K = [&](int j0, int sel) {
        char* Kd = smem + sel * 16384;
#pragma unroll
        for (int t = 0; t < 4; ++t) {
            int iid = w * 4 + t;
            int ldso = iid * 1024 + lane * 16;
            int row = ldso >> 9, inrow = ldso & 511;
            int src = inrow ^ ((row & 7) << 4);
            gld16(Kg + ((size_t)(j0 + row) * 512 + src), Kd + iid * 1024);
        }
    };

    // masks for current tile (9 loads), prefetched one iteration ahead
    int mn[4], mg[4], mc;
    auto MLOAD = [&](int j0) {
#pragma unroll
        for (int r = 0; r < 4; ++r) {
            mn[r] = nrb[r * 2048 + j0 + rl];
            mg[r] = grb[r * 2048 + j0 + rl];
        }
        mc = cmp[j0 + rl];
    };

    STAGE_K(0, 0);
    MLOAD(0);

#pragma unroll 1
    for (int jt = 0; jt < 32; ++jt) {
        const int sel = jt & 1;
        const int j0 = jt * 32;

        // V fragments direct from global (channel-major): 16B coalesced, L2-hot
        s16x8 vl[4], vr[4];
#pragma unroll
        for (int cf = 0; cf < 4; ++cf) {
            size_t off = (size_t)(w * 64 + cf * 16 + rl) * 2048 + (size_t)(j0 + g * 8) * 2;
            vl[cf] = *(const s16x8*)(Vlg + off);
            vr[cf] = *(const s16x8*)(Vrg + off);
        }
        // queue: [STAGE_K(jt)=4, MLOAD(jt)=9, VLOAD=8] -> drain K
        asm volatile("s_waitcnt vmcnt(17)" ::: "memory");
        SBAR();   // (A) K tile visible to all waves

        if (jt < 31) STAGE_K(j0 + 32, sel ^ 1);

        const char* Ks = smem + sel * 16384;
        // S = Q K^T : wave's 16 rows x 16 cols (cols wc*16..+16)
        f32x4 s0 = fz;
#pragma unroll
        for (int kk = 0; kk < 8; ++kk) {
            int jr = wc * 16 + rl;
            s16x8 b0 = *(const s16x8*)(Ks + jr * 512 + ((kk * 64 + g * 16) ^ ((jr & 7) << 4)));
            s0 = mfma16(qf[kk], b0, s0);
        }

        // masks + local max over 16 cols
        const int jq = j0 + wc * 16 + rl;
        const int cmv = mc != 0;
        float sv[4]; int lm[4], rm2[4];
#pragma unroll
        for (int r = 0; r < 4; ++r) {
            int iq = iqb + r;
            int nv = mn[r] != 0, gv = mg[r] != 0;
            int v0 = rmv[r] & cmv & nv;
            int e0 = FINAL ? v0 : (v0 & (int)(iq != jq));
            sv[r] = v0 ? s0[r] * c.scale : -1e30f;
            lm[r] = e0 & gv;  rm2[r] = e0 & (gv ^ 1);
            nbc[r] += (float)e0;
        }
        float tl[4];
#pragma unroll
        for (int r = 0; r < 4; ++r) {
            float t = sv[r];
            t = fmaxf(t, __shfl_xor(t, 1));
            t = fmaxf(t, __shfl_xor(t, 2));
            t = fmaxf(t, __shfl_xor(t, 4));
            t = fmaxf(t, __shfl_xor(t, 8));
            tl[r] = t;
        }
        if (rl == 0) {
            f32x4 tv = {tl[0], tl[1], tl[2], tl[3]};
            *(f32x4*)(mxS + wc * 32 + ws * 16 + g * 4) = tv;
        }
        LGKM0();
        SBAR();   // (M) both col-halves' maxima visible

        f32x4 mo = *(const f32x4*)(mxS + (wc ^ 1) * 32 + ws * 16 + g * 4);
        u16* PlW = (u16*)(smem + 32768 + sel * 2560);
        u16* PrW = (u16*)(smem + 37888 + sel * 2560);
        float rsv[4];
#pragma unroll
        for (int r = 0; r < 4; ++r) {
            float mn2 = fmaxf(mrow[r], fmaxf(tl[r], mo[r]));
            rsv[r] = __expf(mrow[r] - mn2);
            mrow[r] = mn2;
            float e0 = __expf(sv[r] - mn2);
            dden[r] = dden[r] * rsv[r] + e0;
            int prow = ws * 16 + g * 4 + r;
            PlW[prow * 40 + wc * 16 + rl] = lm[r]  ? f2bf(e0) : (u16)0;
            PrW[prow * 40 + wc * 16 + rl] = rm2[r] ? f2bf(e0) : (u16)0;
        }
        if (rl == 0 && wc == 0) {
            f32x4 rv = {rsv[0], rsv[1], rsv[2], rsv[3]};
            *(f32x4*)(rsS + ws * 16 + g * 4) = rv;
        }
        LGKM0();
        SBAR();   // (B) P + rescale visible

        if (jt < 31) MLOAD(j0 + 32);

        // PV: wave's 64-channel slice over all 32 rows
        f32x4 rs4[2];
#pragma unroll
        for (int rf = 0; rf < 2; ++rf) rs4[rf] = *(const f32x4*)(rsS + rf * 16 + g * 4);
#pragma unroll
        for (int rf = 0; rf < 2; ++rf)
#pragma unroll
            for (int cf = 0; cf < 4; ++cf) { accl[rf][cf] *= rs4[rf]; accr[rf][cf] *= rs4[rf]; }
        s16x8 pa[2], pb[2];
#pragma unroll
        for (int rf = 0; rf < 2; ++rf) {
            pa[rf] = *(const s16x8*)((char*)PlW + (rf * 16 + rl) * 80 + g * 16);
            pb[rf] = *(const s16x8*)((char*)PrW + (rf * 16 + rl) * 80 + g * 16);
        }
#pragma unroll
        for (int rf = 0; rf < 2; ++rf)
#pragma unroll
            for (int cf = 0; cf < 4; ++cf) {
                accl[rf][cf] = mfma16(pa[rf], vl[cf], accl[rf][cf]);
                accr[rf][cf] = mfma16(pb[rf], vr[cf], accr[rf][cf]);
            }
    }

    // reduce row stats over rl (16 cols per wave), then across col-halves
#pragma unroll
    for (int r = 0; r < 4; ++r) {
        float d = dden[r];
        d += __shfl_xor(d, 1); d += __shfl_xor(d, 2); d += __shfl_xor(d, 4); d += __shfl_xor(d, 8);
        dden[r] = d;
        float nn = nbc[r];
        nn += __shfl_xor(nn, 1); nn += __shfl_xor(nn, 2); nn += __shfl_xor(nn, 4); nn += __shfl_xor(nn, 8);
        nbc[r] = nn;
    }
    if (rl == 0) {
        f32x4 dv = {dden[0], dden[1], dden[2], dden[3]};
        *(f32x4*)(dpS + wc * 32 + ws * 16 + g * 4) = dv;
        f32x4 nv = {nbc[0], nbc[1], nbc[2], nbc[3]};
        *(f32x4*)(nbpS + wc * 32 + ws * 16 + g * 4) = nv;
    }
    __syncthreads();

    // totals per row (all 32 rows needed by every wave in PV output)
    if (!FINAL) {
        if (rl == 0 && wc == 0) {
            f32x4 n0 = *(const f32x4*)(nbpS + ws * 16 + g * 4);
            f32x4 n1 = *(const f32x4*)(nbpS + 32 + ws * 16 + g * 4);
            f32x4 nt = n0 + n1;
            *(f32x4*)(c.nbOut + b * 1024 + i0 + ws * 16 + g * 4) = nt;
        }
    }
    float bcol[4];
    if (FINAL) {
#pragma unroll
        for (int cf = 0; cf < 4; ++cf) bcol[cf] = bias[w * 64 + cf * 16 + rl];
    }
#pragma unroll
    for (int rf = 0; rf < 2; ++rf) {
        f32x4 d0 = *(const f32x4*)(dpS + rf * 16 + g * 4);
        f32x4 d1 = *(const f32x4*)(dpS + 32 + rf * 16 + g * 4);
        f32x4 dt = d0 + d1;
        f32x4 nbt = fz;
        if (FINAL) {
            f32x4 n0 = *(const f32x4*)(nbpS + rf * 16 + g * 4);
            f32x4 n1 = *(const f32x4*)(nbpS + 32 + rf * 16 + g * 4);
            f32x4 ni = *(const f32x4*)(c.nbIn + b * 1024 + i0 + rf * 16 + g * 4);
            nbt = n0 + n1 + ni;
        }
#pragma unroll
        for (int cf = 0; cf < 4; ++cf) {
            int col = w * 64 + cf * 16 + rl;
#pragma unroll
            for (int r = 0; r < 4; ++r) {
                int row = i0 + rf * 16 + g * 4 + r;
                size_t oi = (size_t)(b * 1024 + row) * 256 + col;
                float inv = dt[r] > 0.f ? 1.f / dt[r] : 0.f;
                float v = (accl[rf][cf][r] + accr[rf][cf][r]) * inv;
                if (!FINAL) {
                    c.io[oi] = v;
                } else {
                    float nb = fmaxf(nbt[r], 1.f);
                    float agg = (c.io[oi] + v) / nb;
                    float sf = bf2f(c.selfTok[oi]) + bcol[cf];
                    c.io[oi] = fmaxf(sf + agg, 0.f);
                }
            }
        }
    }
}

// ---------------- host ----------------
extern "C" void kernel_launch(void* const* d_in, const int* in_sizes, int n_in,
                              void* d_out, int out_size, void* d_ws, size_t ws_size,
                              hipStream_t stream) {
    (void)in_sizes; (void)n_in; (void)out_size; (void)ws_size;
    const float* d_node = (const float*)d_in[0];
    const float* q_node = (const float*)d_in[1];
    const float* b_self = (const float*)d_in[9];
    const int* dm = (const int*)d_in[18];
    const int* qm = (const int*)d_in[19];
    const int* ner = (const int*)d_in[20];
    const int* graph = (const int*)d_in[21];

    char* ws = (char*)d_ws;
    const size_t MB = 1024 * 1024;
    u16* xd   = (u16*)(ws + 0 * MB);
    u16* xq   = (u16*)(ws + 4 * MB);
    u16* wdm  = (u16*)(ws + 8 * MB);
    u16* wqm  = (u16*)(ws + 9 * MB);
    u16* tokd = (u16*)(ws + 10 * MB);
    u16* tokq = (u16*)(ws + 26 * MB);
    u16* vtd  = (u16*)(ws + 42 * MB);
    u16* vtq  = (u16*)(ws + 58 * MB);
    float* nbdd = (float*)(ws + 74 * MB);
    float* nbqq = (float*)(ws + 74 * MB + 32768);

    float* outd = (float*)d_out;
    float* outq = outd + 2097152;

    WPtrs wp;
    wp.p[0]  = (const float*)d_in[2];
    wp.p[1]  = (const float*)d_in[3];
    wp.p[2]  = (const float*)d_in[7];
    wp.p[3]  = (const float*)d_in[8];
    wp.p[4]  = (const float*)d_in[10];
    wp.p[5]  = (const float*)d_in[14];
    wp.p[6]  = (const float*)d_in[13];
    wp.p[7]  = (const float*)d_in[17];
    wp.p[8]  = (const float*)d_in[4];
    wp.p[9]  = (const float*)d_in[5];
    wp.p[10] = (const float*)d_in[6];
    wp.p[11] = (const float*)d_in[8];
    wp.p[12] = (const float*)d_in[11];
    wp.p[13] = (const float*)d_in[15];
    wp.p[14] = (const float*)d_in[12];
    wp.p[15] = (const float*)d_in[16];

    k_conv_w<<<1024, 256, 0, stream>>>(wp, wdm, wqm);
    k_conv_x<<<4096, 256, 0, stream>>>(d_node, q_node, xd, xq);
    k_proj<<<dim3(64, 2, 16), 256, 0, stream>>>(xd, xq, wdm, wqm, tokd, tokq, vtd, vtq);

    const size_t M2 = 2097152;
    PhaseCfg dd = { tokd, tokd + M2, vtd, vtd + M2, dm, dm, 0, 0, 0.0625f,
                    outd, nbdd, nullptr, nullptr };
    PhaseCfg qq = { tokq, tokq + M2, vtq, vtq + M2, qm, qm, 1024, 1024, 0.0625f,
                    outq, nbqq, nullptr, nullptr };
    k_attn<false><<<dim3(32, 8, 2), 256, 0, stream>>>(dd, qq, ner, graph, b_self);

    PhaseCfg dq = { d_node, tokq + 2 * M2, vtq + 2 * M2, vtq + 3 * M2, dm, qm, 0, 1024, 1.0f,
                    outd, nullptr, nbdd, tokd + 3 * M2 };
    PhaseCfg qd = { q_node, tokd + 2 * M2, vtd + 2 * M2, vtd + 3 * M2, qm, dm, 1024, 0, 1.0f,
                    outq, nullptr, nbqq, tokq + 3 * M2 };
    k_attn<true><<<dim3(32, 8, 2), 256, 0, stream>>>(dq, qd, ner, graph, b_self);
}